// Round 1
// baseline (2972.943 us; speedup 1.0000x reference)
//
#include <hip/hip_runtime.h>
#include <hip/hip_bf16.h>

#define DD 128
#define TM 64
#define LDX 136   // 128 + 8 pad (u16 elems) -> row stride 272B, 2-way bank alias (free)

#define NV   100000
#define NLIT 200000
#define NCLS 420000

typedef __attribute__((ext_vector_type(4))) float f32x4;
typedef __attribute__((ext_vector_type(8))) short bf16x8;

__device__ __forceinline__ float bf2f(unsigned short u) {
    union { unsigned int i; float f; } v; v.i = ((unsigned int)u) << 16; return v.f;
}
__device__ __forceinline__ unsigned short f2bf(float f) {
    union { float f; unsigned int i; } v; v.f = f;
    return (unsigned short)((v.i + 0x7FFFu + ((v.i >> 16) & 1u)) >> 16);
}

// MODE: 0 = Lmsg (emb[0:2V] -> l_all bf16)
//       1 = Cup  (concat(emb[2V:], gather3(l_all)) -> d_out[2V:] f32)
//       2 = Cmsg (c_new -> c_all bf16)
//       3 = Lup  (concat(emb[0:2V], cl_msg, flip(l_all)) -> d_out[0:2V] f32)
template<int MODE>
__global__ __launch_bounds__(256, 2)
void mlp3_kernel(const float* __restrict__ x0, const float* __restrict__ x1,
                 const unsigned short* __restrict__ lall,
                 const int* __restrict__ elit,
                 const float* __restrict__ W1, const float* __restrict__ Wh,
                 const float* __restrict__ bias,
                 float* __restrict__ outf, unsigned short* __restrict__ outb,
                 int M)
{
    constexpr int NCHUNK = (MODE == 1) ? 2 : (MODE == 3) ? 3 : 1;
    constexpr bool OUTB = (MODE == 0 || MODE == 2);

    __shared__ alignas(16) unsigned short xa[TM][LDX];
    __shared__ alignas(16) unsigned short xb[TM][LDX];
    __shared__ alignas(16) unsigned short wT[DD][LDX];

    const int tid  = threadIdx.x;
    const int row0 = blockIdx.x * TM;
    const int lane = tid & 63;
    const int m0   = (tid >> 6) * 16;
    const int l15  = lane & 15;
    const int kg   = (lane >> 4) * 8;

    f32x4 acc[8];

    // wT[n][k] = W[k][n]  (bf16)
    auto stage_w = [&](const float* Wp) {
        #pragma unroll
        for (int i = 0; i < 16; ++i) {
            int e = (i * 256 + tid) * 4;
            int k = e >> 7, n = e & 127;
            const float4 w4 = *(const float4*)(Wp + k * DD + n);
            wT[n+0][k] = f2bf(w4.x);
            wT[n+1][k] = f2bf(w4.y);
            wT[n+2][k] = f2bf(w4.z);
            wT[n+3][k] = f2bf(w4.w);
        }
    };

    auto stage_f32 = [&](const float* src) {
        int col = (tid & 31) * 4;
        int rr  = tid >> 5;
        #pragma unroll
        for (int i = 0; i < 8; ++i) {
            int r = i * 8 + rr;
            int gr = row0 + r;
            float4 v = make_float4(0.f, 0.f, 0.f, 0.f);
            if (gr < M) v = *(const float4*)(src + (size_t)gr * DD + col);
            xa[r][col+0] = f2bf(v.x);
            xa[r][col+1] = f2bf(v.y);
            xa[r][col+2] = f2bf(v.z);
            xa[r][col+3] = f2bf(v.w);
        }
    };

    auto compute = [&](unsigned short (*x)[LDX]) {
        const int ar = m0 + l15;
        #pragma unroll
        for (int kk = 0; kk < 4; ++kk) {
            bf16x8 a = *(const bf16x8*)&x[ar][kk * 32 + kg];
            #pragma unroll
            for (int nt = 0; nt < 8; ++nt) {
                bf16x8 b = *(const bf16x8*)&wT[nt * 16 + l15][kk * 32 + kg];
                acc[nt] = __builtin_amdgcn_mfma_f32_16x16x32_bf16(a, b, acc[nt], 0, 0, 0);
            }
        }
    };

    auto epi_lds = [&](const float* bvec, unsigned short (*xout)[LDX]) {
        #pragma unroll
        for (int nt = 0; nt < 8; ++nt) {
            int col = nt * 16 + l15;
            float bv = bvec[col];
            #pragma unroll
            for (int r = 0; r < 4; ++r) {
                float v = acc[nt][r] + bv;
                v = fmaxf(v, 0.f);
                xout[m0 + (lane >> 4) * 4 + r][col] = f2bf(v);
            }
        }
    };

    // ---------------- layer 0 (K-chunked over NCHUNK*128) ----------------
    #pragma unroll
    for (int i = 0; i < 8; ++i) acc[i] = (f32x4){0.f, 0.f, 0.f, 0.f};

    for (int kc = 0; kc < NCHUNK; ++kc) {
        __syncthreads();
        stage_w(W1 + kc * DD * DD);
        if constexpr (MODE == 0 || MODE == 2) {
            stage_f32(x0);
        } else if constexpr (MODE == 1) {
            if (kc == 0) stage_f32(x0);
            else {
                // lc_msg: sum of 3 gathered literal-message rows per clause
                int r  = tid >> 2;
                int c0 = (tid & 3) * 32;
                int gc = row0 + r;
                float accg[32];
                #pragma unroll
                for (int q = 0; q < 32; ++q) accg[q] = 0.f;
                if (gc < M) {
                    #pragma unroll
                    for (int j = 0; j < 3; ++j) {
                        int lit = elit[3 * gc + j];
                        const unsigned short* p = lall + (size_t)lit * DD + c0;
                        #pragma unroll
                        for (int q8 = 0; q8 < 4; ++q8) {
                            bf16x8 vv = *(const bf16x8*)(p + q8 * 8);
                            #pragma unroll
                            for (int t = 0; t < 8; ++t)
                                accg[q8 * 8 + t] += bf2f((unsigned short)vv[t]);
                        }
                    }
                }
                #pragma unroll
                for (int q = 0; q < 32; ++q) xa[r][c0 + q] = f2bf(accg[q]);
            }
        } else { // MODE == 3
            if (kc == 0) stage_f32(x0);
            else if (kc == 1) stage_f32(x1);
            else {
                // l_flip_msg: row r -> l_all[(r<V) ? r+V : r-V]
                int col = (tid & 31) * 4;
                int rr  = tid >> 5;
                #pragma unroll
                for (int i = 0; i < 8; ++i) {
                    int r = i * 8 + rr;
                    int gr = row0 + r;
                    int sr = (gr < NV) ? gr + NV : gr - NV;
                    ushort4 v = *(const ushort4*)(lall + (size_t)sr * DD + col);
                    *(ushort4*)&xa[r][col] = v;
                }
            }
        }
        __syncthreads();
        compute(xa);
    }
    epi_lds(bias, xb);

    // ---------------- layer 1 ----------------
    __syncthreads();
    stage_w(Wh);
    __syncthreads();
    #pragma unroll
    for (int i = 0; i < 8; ++i) acc[i] = (f32x4){0.f, 0.f, 0.f, 0.f};
    compute(xb);
    epi_lds(bias + DD, xa);

    // ---------------- layer 2 (no relu, write global) ----------------
    __syncthreads();
    stage_w(Wh + DD * DD);
    __syncthreads();
    #pragma unroll
    for (int i = 0; i < 8; ++i) acc[i] = (f32x4){0.f, 0.f, 0.f, 0.f};
    compute(xa);

    #pragma unroll
    for (int nt = 0; nt < 8; ++nt) {
        int col = nt * 16 + l15;
        float bv = bias[2 * DD + col];
        #pragma unroll
        for (int r = 0; r < 4; ++r) {
            int gr = row0 + m0 + (lane >> 4) * 4 + r;
            if (gr < M) {
                float v = acc[nt][r] + bv;
                if constexpr (OUTB) outb[(size_t)gr * DD + col] = f2bf(v);
                else               outf[(size_t)gr * DD + col] = v;
            }
        }
    }
}

// cl_msg[lit] += c_all[clause] for each of the 3 edges of each clause
__global__ __launch_bounds__(256)
void scatter_cl_kernel(const unsigned short* __restrict__ call,
                       const int* __restrict__ elit,
                       float* __restrict__ cl, int C)
{
    int lane = threadIdx.x & 63;
    int c = blockIdx.x * 4 + (threadIdx.x >> 6);
    if (c >= C) return;
    int c0 = lane * 2;
    unsigned int packed = *(const unsigned int*)(call + (size_t)c * DD + c0);
    float v0 = bf2f((unsigned short)(packed & 0xFFFFu));
    float v1 = bf2f((unsigned short)(packed >> 16));
    #pragma unroll
    for (int j = 0; j < 3; ++j) {
        int lit = elit[3 * c + j];
        float* p = cl + (size_t)lit * DD + c0;
        atomicAdd(p, v0);
        atomicAdd(p + 1, v1);
    }
}

extern "C" void kernel_launch(void* const* d_in, const int* in_sizes, int n_in,
                              void* d_out, int out_size, void* d_ws, size_t ws_size,
                              hipStream_t stream)
{
    const float* emb    = (const float*)d_in[0];
    const int*   elit   = (const int*)d_in[2];
    const float* Lmsg_W = (const float*)d_in[6];
    const float* Lmsg_b = (const float*)d_in[7];
    const float* Cmsg_W = (const float*)d_in[8];
    const float* Cmsg_b = (const float*)d_in[9];
    const float* Cup_W1 = (const float*)d_in[10];
    const float* Cup_Wh = (const float*)d_in[11];
    const float* Cup_b  = (const float*)d_in[12];
    const float* Lup_W1 = (const float*)d_in[13];
    const float* Lup_Wh = (const float*)d_in[14];
    const float* Lup_b  = (const float*)d_in[15];

    float* out   = (float*)d_out;
    float* c_new = out + (size_t)NLIT * DD;

    unsigned short* l_all = (unsigned short*)d_ws;
    unsigned short* c_all = (unsigned short*)((char*)d_ws + (size_t)NLIT * DD * 2);
    float*          cl    = (float*)((char*)d_ws + (size_t)NLIT * DD * 2 + (size_t)NCLS * DD * 2);

    hipMemsetAsync(cl, 0, (size_t)NLIT * DD * sizeof(float), stream);

    // 1) l_all_msg = mlp3(emb[0:2V], Lmsg)          -> ws (bf16)
    mlp3_kernel<0><<<NLIT / TM, 256, 0, stream>>>(emb, nullptr, nullptr, nullptr,
        Lmsg_W, Lmsg_W + DD * DD, Lmsg_b, nullptr, l_all, NLIT);

    // 2) c_new = mlp3(concat(emb[2V:], lc_msg), Cup) -> d_out[2V:] (f32); lc gather fused
    mlp3_kernel<1><<<(NCLS + TM - 1) / TM, 256, 0, stream>>>(emb + (size_t)NLIT * DD, nullptr,
        l_all, elit, Cup_W1, Cup_Wh, Cup_b, c_new, nullptr, NCLS);

    // 3) c_all_msg = mlp3(c_new, Cmsg)               -> ws (bf16)
    mlp3_kernel<2><<<(NCLS + TM - 1) / TM, 256, 0, stream>>>(c_new, nullptr, nullptr, nullptr,
        Cmsg_W, Cmsg_W + DD * DD, Cmsg_b, nullptr, c_all, NCLS);

    // 4) cl_msg = scatter-add over edges             -> ws (f32)
    scatter_cl_kernel<<<(NCLS + 3) / 4, 256, 0, stream>>>(c_all, elit, cl, NCLS);

    // 5) l_new = mlp3(concat(emb[0:2V], cl_msg, flip(l_all)), Lup) -> d_out[0:2V] (f32)
    mlp3_kernel<3><<<NLIT / TM, 256, 0, stream>>>(emb, cl, l_all, elit,
        Lup_W1, Lup_Wh, Lup_b, out, nullptr, NLIT);
}